// Round 5
// baseline (418.529 us; speedup 1.0000x reference)
//
#include <hip/hip_runtime.h>
#include <cstdint>
#include <cstddef>

// ---------------------------------------------------------------------------
// GCN+LPA on MI355X.
// R5: R4 profile showed all kernels <41us; budget dominated by 7 gather spmms
// at ~20G cache-lines/s (~28 cyc/edge: ~6 VALU + ~22 unhidden latency).
// Fix: 2 rows per wave with joint 8+8 gather bursts -> 2x memory-level
// parallelism per wave (16 lines in flight for F=64, 32 for F=128).
// Also: fuse x f32->bf16 convert into gemm128 (in-register cvt before MFMA).
// NOTE: packing assumes N < 65536 (row/col fit 16 bits). N = 50000 here.
// ---------------------------------------------------------------------------

#define WS_ALIGN(x) (((x) + 255) & ~((size_t)255))

typedef __attribute__((ext_vector_type(8))) short short8;
typedef __attribute__((ext_vector_type(4))) float floatx4;

__device__ __forceinline__ unsigned short f2bf(float f) {
    unsigned u = __float_as_uint(f);
    u += 0x7fffu + ((u >> 16) & 1u);          // round-to-nearest-even
    return (unsigned short)(u >> 16);
}
__device__ __forceinline__ float bf2f(unsigned short h) {
    return __uint_as_float(((unsigned)h) << 16);
}
__device__ __forceinline__ float sigmoidf(float x) {
    return 1.f / (1.f + __expf(-x));
}

static const int NBLK = 256;   // blocks for binning passes
#define MAXNB 256              // max coarse buckets supported (N <= 65536)

// ---------------------------------------------------------------------------
// CSR build: 2-level counting sort, LDS atomics only.
// ---------------------------------------------------------------------------
__launch_bounds__(256)
__global__ void binA_count(const int* __restrict__ row, int* __restrict__ bucket_count,
                           int* __restrict__ bases, int E, int chunk, int NB)
{
    __shared__ int hist[MAXNB];
    const int t = threadIdx.x;
    const int blk = blockIdx.x;
    if (t < NB) hist[t] = 0;
    __syncthreads();
    const int s = blk * chunk;
    const int e = min(E, s + chunk);
    for (int i = s + t; i < e; i += 256)
        atomicAdd(&hist[row[i] >> 8], 1);
    __syncthreads();
    if (t < NB)
        bases[blk * NB + t] = atomicAdd(&bucket_count[t], hist[t]);
}

__launch_bounds__(256)
__global__ void bin_scan(const int* __restrict__ bucket_count, int* __restrict__ bucket_start,
                         int NB)
{
    __shared__ int s[256];
    const int t = threadIdx.x;
    int v = (t < NB) ? bucket_count[t] : 0;
    s[t] = v;
    __syncthreads();
    for (int off = 1; off < 256; off <<= 1) {
        int u = (t >= off) ? s[t - off] : 0;
        __syncthreads();
        s[t] += u;
        __syncthreads();
    }
    int excl = s[t] - v;
    if (t <= NB) bucket_start[t] = excl;   // t==NB: total == E
}

__launch_bounds__(256)
__global__ void binA_scatter(const int* __restrict__ row, const int* __restrict__ colv,
                             const float* __restrict__ ea,
                             const int* __restrict__ bucket_start, const int* __restrict__ bases,
                             int2* __restrict__ bk, int E, int chunk, int NB)
{
    __shared__ int cur[MAXNB];
    const int t = threadIdx.x;
    const int blk = blockIdx.x;
    if (t < NB) cur[t] = bucket_start[t] + bases[blk * NB + t];
    __syncthreads();
    const int s = blk * chunk;
    const int e = min(E, s + chunk);
    for (int i = s + t; i < e; i += 256) {
        int r = row[i];
        int bin = r >> 8;
        int pos = atomicAdd(&cur[bin], 1);
        bk[pos] = make_int2(((r & 255) << 16) | colv[i], __float_as_int(ea[i]));
    }
}

__launch_bounds__(256)
__global__ void binB(const int2* __restrict__ bk, const int* __restrict__ bucket_start,
                     int* __restrict__ rowptr, int2* __restrict__ edges, int N)
{
    __shared__ int cnt[256];
    __shared__ float deg[256];
    __shared__ float inv[256];
    __shared__ int excl_s[256];
    __shared__ int cur[256];
    __shared__ int scantmp[256];
    const int b = blockIdx.x;
    const int t = threadIdx.x;
    const int s = bucket_start[b];
    const int e = bucket_start[b + 1];
    cnt[t] = 0;
    deg[t] = 0.f;
    __syncthreads();
    for (int i = s + t; i < e; i += 256) {
        int2 v = bk[i];
        int rl = ((unsigned)v.x) >> 16;
        atomicAdd(&cnt[rl], 1);
        atomicAdd(&deg[rl], __int_as_float(v.y));
    }
    __syncthreads();
    const int myc = cnt[t];
    scantmp[t] = myc;
    __syncthreads();
    for (int off = 1; off < 256; off <<= 1) {
        int u = (t >= off) ? scantmp[t - off] : 0;
        __syncthreads();
        scantmp[t] += u;
        __syncthreads();
    }
    const int excl = scantmp[t] - myc;
    excl_s[t] = excl;
    float d = deg[t];
    inv[t] = (d > 0.f) ? 1.f / d : 0.f;
    cur[t] = 0;
    const int gr = b * 256 + t;
    if (gr <= N) rowptr[gr] = s + excl;
    __syncthreads();
    for (int i = s + t; i < e; i += 256) {
        int2 v = bk[i];
        int rl = ((unsigned)v.x) >> 16;
        int c = v.x & 0xffff;
        int p = s + excl_s[rl] + atomicAdd(&cur[rl], 1);
        edges[p] = make_int2(c, __float_as_int(__int_as_float(v.y) * inv[rl]));
    }
}

// ---------------------------------------------------------------------------
// Conversions / packing
// ---------------------------------------------------------------------------
__global__ void f32_to_bf16_kernel(const float* __restrict__ in, unsigned short* __restrict__ out,
                                   int n2)  // n2 = n/2 pairs
{
    int i = blockIdx.x * 256 + threadIdx.x;
    if (i < n2) {
        float2 v = ((const float2*)in)[i];
        unsigned p = (unsigned)f2bf(v.x) | ((unsigned)f2bf(v.y) << 16);
        ((unsigned*)out)[i] = p;
    }
}

// Pre-pack W[128,COLS] f32 -> bf16 in MFMA B-fragment order.
// frag index idx = (ct*4 + t)*64 + lane; element j: W[t*32 + (lane>>4)*8 + j][ct*16 + (lane&15)]
template<int COLS>
__global__ void pack_w_kernel(const float* __restrict__ W, unsigned short* __restrict__ Wp)
{
    const int total = (COLS / 16) * 4 * 64;
    int idx = blockIdx.x * 256 + threadIdx.x;
    if (idx >= total) return;
    const int l = idx & 63;
    const int t = (idx >> 6) & 3;
    const int ct = idx >> 8;
    const int kbase = t * 32 + (l >> 4) * 8;
    const int col = ct * 16 + (l & 15);
    unsigned short v[8];
#pragma unroll
    for (int j = 0; j < 8; ++j)
        v[j] = f2bf(W[(size_t)(kbase + j) * COLS + col]);
    uint4 o;
    o.x = (unsigned)v[0] | ((unsigned)v[1] << 16);
    o.y = (unsigned)v[2] | ((unsigned)v[3] << 16);
    o.z = (unsigned)v[4] | ((unsigned)v[5] << 16);
    o.w = (unsigned)v[6] | ((unsigned)v[7] << 16);
    *(uint4*)(Wp + (size_t)idx * 8) = o;
}

// ---------------------------------------------------------------------------
// MFMA GEMM (f32 A, fused cvt): C_bf16[M,COLS] = bf16(A_f32[M,128]) @ Wp.
// 4 waves/block, wave = 16 rows x COLS, K=128 in 4 k-tiles. No LDS.
// ---------------------------------------------------------------------------
template<int COLS>
__launch_bounds__(256)
__global__ void gemm_mfma_f32a(const float* __restrict__ A,
                               const unsigned short* __restrict__ Wp,
                               unsigned short* __restrict__ C, int M)
{
    const int wave = threadIdx.x >> 6;
    const int lane = threadIdx.x & 63;
    const int row0 = blockIdx.x * 64 + wave * 16;
    const int m = lane & 15;
    const int q = lane >> 4;

    const int arow = row0 + m;
    const bool avalid = arow < M;
    short8 a[4];
#pragma unroll
    for (int t = 0; t < 4; ++t) {
        if (avalid) {
            float4 f0 = *(const float4*)(A + (size_t)arow * 128 + t * 32 + q * 8);
            float4 f1 = *(const float4*)(A + (size_t)arow * 128 + t * 32 + q * 8 + 4);
            a[t][0] = (short)f2bf(f0.x); a[t][1] = (short)f2bf(f0.y);
            a[t][2] = (short)f2bf(f0.z); a[t][3] = (short)f2bf(f0.w);
            a[t][4] = (short)f2bf(f1.x); a[t][5] = (short)f2bf(f1.y);
            a[t][6] = (short)f2bf(f1.z); a[t][7] = (short)f2bf(f1.w);
        } else {
            a[t] = (short8)0;
        }
    }

#pragma unroll
    for (int ct = 0; ct < COLS / 16; ++ct) {
        floatx4 acc = {0.f, 0.f, 0.f, 0.f};
#pragma unroll
        for (int t = 0; t < 4; ++t) {
            short8 b = *(const short8*)(Wp + (size_t)((ct * 4 + t) * 64 + lane) * 8);
            acc = __builtin_amdgcn_mfma_f32_16x16x32_bf16(a[t], b, acc, 0, 0, 0);
        }
        const int col = ct * 16 + m;
#pragma unroll
        for (int r = 0; r < 4; ++r) {
            int orow = row0 + q * 4 + r;
            if (orow < M)
                C[(size_t)orow * COLS + col] = f2bf(acc[r]);
        }
    }
}

// MFMA GEMM (bf16 A): same structure, A already bf16.
template<int COLS>
__launch_bounds__(256)
__global__ void gemm_mfma(const unsigned short* __restrict__ A,
                          const unsigned short* __restrict__ Wp,
                          unsigned short* __restrict__ C, int M)
{
    const int wave = threadIdx.x >> 6;
    const int lane = threadIdx.x & 63;
    const int row0 = blockIdx.x * 64 + wave * 16;
    const int m = lane & 15;
    const int q = lane >> 4;

    const int arow = row0 + m;
    const bool avalid = arow < M;
    short8 a[4];
#pragma unroll
    for (int t = 0; t < 4; ++t) {
        if (avalid)
            a[t] = *(const short8*)(A + (size_t)arow * 128 + t * 32 + q * 8);
        else
            a[t] = (short8)0;
    }

#pragma unroll
    for (int ct = 0; ct < COLS / 16; ++ct) {
        floatx4 acc = {0.f, 0.f, 0.f, 0.f};
#pragma unroll
        for (int t = 0; t < 4; ++t) {
            short8 b = *(const short8*)(Wp + (size_t)((ct * 4 + t) * 64 + lane) * 8);
            acc = __builtin_amdgcn_mfma_f32_16x16x32_bf16(a[t], b, acc, 0, 0, 0);
        }
        const int col = ct * 16 + m;
#pragma unroll
        for (int r = 0; r < 4; ++r) {
            int orow = row0 + q * 4 + r;
            if (orow < M)
                C[(size_t)orow * COLS + col] = f2bf(acc[r]);
        }
    }
}

// ---------------------------------------------------------------------------
// SpMM F=128, bf16 src, bias+relu, bf16 packed output.
// 2 rows per wave, joint 8+8 gather bursts (32 cache lines in flight).
// ---------------------------------------------------------------------------
__launch_bounds__(256)
__global__ void spmm128_relu(const int* __restrict__ rowptr, const int2* __restrict__ edges,
                             const unsigned short* __restrict__ src,
                             const float* __restrict__ bias, unsigned* __restrict__ out, int n)
{
    const int wave = threadIdx.x >> 6;
    const int lane = threadIdx.x & 63;
    const int r0 = blockIdx.x * 8 + wave * 2;
    const int r1 = r0 + 1;
    if (r0 >= n) return;
    const bool has1 = (r1 < n);
    const int s0 = rowptr[r0];
    const int e0 = rowptr[r0 + 1];
    int s1 = 0, e1 = 0;
    if (has1) { s1 = rowptr[r1]; e1 = rowptr[r1 + 1]; }
    const unsigned* us = (const unsigned*)src;   // 64 uints / row

    float ax0[4], ay0[4], ax1[4], ay1[4];
#pragma unroll
    for (int j = 0; j < 4; ++j) { ax0[j] = 0.f; ay0[j] = 0.f; ax1[j] = 0.f; ay1[j] = 0.f; }

    int i0 = s0, i1 = s1;
    // joint burst: 8 edges per row -> 16 gathers (32 lines) in flight
    while (i0 + 8 <= e0 && i1 + 8 <= e1) {
        int2 ed0[8], ed1[8];
#pragma unroll
        for (int j = 0; j < 8; ++j) ed0[j] = edges[i0 + j];
#pragma unroll
        for (int j = 0; j < 8; ++j) ed1[j] = edges[i1 + j];
        unsigned u0[8], u1[8];
#pragma unroll
        for (int j = 0; j < 8; ++j) u0[j] = us[(size_t)ed0[j].x * 64 + lane];
#pragma unroll
        for (int j = 0; j < 8; ++j) u1[j] = us[(size_t)ed1[j].x * 64 + lane];
#pragma unroll
        for (int j = 0; j < 8; ++j) {
            float w0 = __int_as_float(ed0[j].y);
            float w1 = __int_as_float(ed1[j].y);
            ax0[j & 3] = fmaf(w0, __uint_as_float(u0[j] << 16), ax0[j & 3]);
            ay0[j & 3] = fmaf(w0, __uint_as_float(u0[j] & 0xffff0000u), ay0[j & 3]);
            ax1[j & 3] = fmaf(w1, __uint_as_float(u1[j] << 16), ax1[j & 3]);
            ay1[j & 3] = fmaf(w1, __uint_as_float(u1[j] & 0xffff0000u), ay1[j & 3]);
        }
        i0 += 8; i1 += 8;
    }
    // drain r0
    while (i0 + 8 <= e0) {
        int2 ed[8]; unsigned u[8];
#pragma unroll
        for (int j = 0; j < 8; ++j) ed[j] = edges[i0 + j];
#pragma unroll
        for (int j = 0; j < 8; ++j) u[j] = us[(size_t)ed[j].x * 64 + lane];
#pragma unroll
        for (int j = 0; j < 8; ++j) {
            float w = __int_as_float(ed[j].y);
            ax0[j & 3] = fmaf(w, __uint_as_float(u[j] << 16), ax0[j & 3]);
            ay0[j & 3] = fmaf(w, __uint_as_float(u[j] & 0xffff0000u), ay0[j & 3]);
        }
        i0 += 8;
    }
    for (; i0 < e0; ++i0) {
        int2 e = edges[i0];
        unsigned u = us[(size_t)e.x * 64 + lane];
        float w = __int_as_float(e.y);
        ax0[0] = fmaf(w, __uint_as_float(u << 16), ax0[0]);
        ay0[0] = fmaf(w, __uint_as_float(u & 0xffff0000u), ay0[0]);
    }
    // drain r1
    while (i1 + 8 <= e1) {
        int2 ed[8]; unsigned u[8];
#pragma unroll
        for (int j = 0; j < 8; ++j) ed[j] = edges[i1 + j];
#pragma unroll
        for (int j = 0; j < 8; ++j) u[j] = us[(size_t)ed[j].x * 64 + lane];
#pragma unroll
        for (int j = 0; j < 8; ++j) {
            float w = __int_as_float(ed[j].y);
            ax1[j & 3] = fmaf(w, __uint_as_float(u[j] << 16), ax1[j & 3]);
            ay1[j & 3] = fmaf(w, __uint_as_float(u[j] & 0xffff0000u), ay1[j & 3]);
        }
        i1 += 8;
    }
    for (; i1 < e1; ++i1) {
        int2 e = edges[i1];
        unsigned u = us[(size_t)e.x * 64 + lane];
        float w = __int_as_float(e.y);
        ax1[0] = fmaf(w, __uint_as_float(u << 16), ax1[0]);
        ay1[0] = fmaf(w, __uint_as_float(u & 0xffff0000u), ay1[0]);
    }

    float2 b = *(const float2*)(bias + lane * 2);
    float vx = (ax0[0] + ax0[1]) + (ax0[2] + ax0[3]);
    float vy = (ay0[0] + ay0[1]) + (ay0[2] + ay0[3]);
    vx = fmaxf(vx + b.x, 0.f);
    vy = fmaxf(vy + b.y, 0.f);
    out[(size_t)r0 * 64 + lane] = (unsigned)f2bf(vx) | ((unsigned)f2bf(vy) << 16);
    if (has1) {
        float wx = (ax1[0] + ax1[1]) + (ax1[2] + ax1[3]);
        float wy = (ay1[0] + ay1[1]) + (ay1[2] + ay1[3]);
        wx = fmaxf(wx + b.x, 0.f);
        wy = fmaxf(wy + b.y, 0.f);
        out[(size_t)r1 * 64 + lane] = (unsigned)f2bf(wx) | ((unsigned)f2bf(wy) << 16);
    }
}

// ---------------------------------------------------------------------------
// SpMM F=64, bf16 src. ACT: 0 none, 2 bias+sigmoid, 3 sigmoid.
// OUT_BF16: store bf16 else f32. 2 rows per wave, joint 8+8 bursts.
// ---------------------------------------------------------------------------
template<int ACT, bool OUT_BF16>
__launch_bounds__(256)
__global__ void spmm64_kernel(const int* __restrict__ rowptr, const int2* __restrict__ edges,
                              const unsigned short* __restrict__ src,
                              const float* __restrict__ bias, void* __restrict__ out, int n)
{
    const int wave = threadIdx.x >> 6;
    const int lane = threadIdx.x & 63;
    const int r0 = blockIdx.x * 8 + wave * 2;
    const int r1 = r0 + 1;
    if (r0 >= n) return;
    const bool has1 = (r1 < n);
    const int s0 = rowptr[r0];
    const int e0 = rowptr[r0 + 1];
    int s1 = 0, e1 = 0;
    if (has1) { s1 = rowptr[r1]; e1 = rowptr[r1 + 1]; }

    float a0[4], a1[4];
#pragma unroll
    for (int j = 0; j < 4; ++j) { a0[j] = 0.f; a1[j] = 0.f; }

    int i0 = s0, i1 = s1;
    while (i0 + 8 <= e0 && i1 + 8 <= e1) {
        int2 ed0[8], ed1[8];
#pragma unroll
        for (int j = 0; j < 8; ++j) ed0[j] = edges[i0 + j];
#pragma unroll
        for (int j = 0; j < 8; ++j) ed1[j] = edges[i1 + j];
        float sv0[8], sv1[8];
#pragma unroll
        for (int j = 0; j < 8; ++j) sv0[j] = bf2f(src[(size_t)ed0[j].x * 64 + lane]);
#pragma unroll
        for (int j = 0; j < 8; ++j) sv1[j] = bf2f(src[(size_t)ed1[j].x * 64 + lane]);
#pragma unroll
        for (int j = 0; j < 8; ++j) {
            a0[j & 3] = fmaf(__int_as_float(ed0[j].y), sv0[j], a0[j & 3]);
            a1[j & 3] = fmaf(__int_as_float(ed1[j].y), sv1[j], a1[j & 3]);
        }
        i0 += 8; i1 += 8;
    }
    while (i0 + 8 <= e0) {
        int2 ed[8]; float sv[8];
#pragma unroll
        for (int j = 0; j < 8; ++j) ed[j] = edges[i0 + j];
#pragma unroll
        for (int j = 0; j < 8; ++j) sv[j] = bf2f(src[(size_t)ed[j].x * 64 + lane]);
#pragma unroll
        for (int j = 0; j < 8; ++j) a0[j & 3] = fmaf(__int_as_float(ed[j].y), sv[j], a0[j & 3]);
        i0 += 8;
    }
    for (; i0 < e0; ++i0) {
        int2 e = edges[i0];
        a0[0] = fmaf(__int_as_float(e.y), bf2f(src[(size_t)e.x * 64 + lane]), a0[0]);
    }
    while (i1 + 8 <= e1) {
        int2 ed[8]; float sv[8];
#pragma unroll
        for (int j = 0; j < 8; ++j) ed[j] = edges[i1 + j];
#pragma unroll
        for (int j = 0; j < 8; ++j) sv[j] = bf2f(src[(size_t)ed[j].x * 64 + lane]);
#pragma unroll
        for (int j = 0; j < 8; ++j) a1[j & 3] = fmaf(__int_as_float(ed[j].y), sv[j], a1[j & 3]);
        i1 += 8;
    }
    for (; i1 < e1; ++i1) {
        int2 e = edges[i1];
        a1[0] = fmaf(__int_as_float(e.y), bf2f(src[(size_t)e.x * 64 + lane]), a1[0]);
    }

    float v0 = (a0[0] + a0[1]) + (a0[2] + a0[3]);
    float v1 = (a1[0] + a1[1]) + (a1[2] + a1[3]);
    if (ACT == 2) { float b = bias[lane]; v0 = sigmoidf(v0 + b); v1 = sigmoidf(v1 + b); }
    else if (ACT == 3) { v0 = sigmoidf(v0); v1 = sigmoidf(v1); }
    if (OUT_BF16) {
        ((unsigned short*)out)[(size_t)r0 * 64 + lane] = f2bf(v0);
        if (has1) ((unsigned short*)out)[(size_t)r1 * 64 + lane] = f2bf(v1);
    } else {
        ((float*)out)[(size_t)r0 * 64 + lane] = v0;
        if (has1) ((float*)out)[(size_t)r1 * 64 + lane] = v1;
    }
}

// ---------------------------------------------------------------------------
extern "C" void kernel_launch(void* const* d_in, const int* in_sizes, int n_in,
                              void* d_out, int out_size, void* d_ws, size_t ws_size,
                              hipStream_t stream)
{
    const float* x    = (const float*)d_in[0];
    const float* soft = (const float*)d_in[1];
    const float* ea   = (const float*)d_in[2];
    const float* w1   = (const float*)d_in[3];
    const float* b1   = (const float*)d_in[4];
    const float* w2   = (const float*)d_in[5];
    const float* b2   = (const float*)d_in[6];
    const int*   eidx = (const int*)d_in[7];

    const int N = in_sizes[0] / 128;
    const int E = in_sizes[2];
    const int* row  = eidx;
    const int* colv = eidx + E;
    const int NB = (N + 255) / 256;            // coarse buckets (<= 256)
    const int chunk = (E + NBLK - 1) / NBLK;

    uint8_t* ws = (uint8_t*)d_ws;
    size_t off = 0;
    auto alloc = [&](size_t bytes) -> void* {
        void* p = ws + off;
        off += WS_ALIGN(bytes);
        return p;
    };
    int*  bucket_count = (int*) alloc((size_t)NB * 4);
    int*  bucket_start = (int*) alloc(((size_t)NB + 1) * 4);
    int*  bases        = (int*) alloc((size_t)NBLK * NB * 4);
    int*  rowptr       = (int*) alloc(((size_t)N + 1) * 4);
    int2* bk           = (int2*)alloc((size_t)E * 8);
    int2* edges        = (int2*)alloc((size_t)E * 8);
    unsigned short* w1p     = (unsigned short*)alloc((size_t)128 * 128 * 2);
    unsigned short* w2p     = (unsigned short*)alloc((size_t)128 * 64 * 2);
    unsigned short* xw1b    = (unsigned short*)alloc((size_t)N * 128 * 2);
    unsigned short* hb      = (unsigned short*)alloc((size_t)N * 128 * 2);
    unsigned short* logitsb = (unsigned short*)alloc((size_t)N * 64 * 2);
    unsigned short* softb   = (unsigned short*)alloc((size_t)N * 64 * 2);
    unsigned short* labA    = (unsigned short*)alloc((size_t)N * 64 * 2);
    unsigned short* labB    = (unsigned short*)alloc((size_t)N * 64 * 2);

    float* out0 = (float*)d_out;             // x_out [N,64]
    float* out1 = out0 + (size_t)N * 64;     // labels [N,64]

    hipMemsetAsync(bucket_count, 0, (size_t)NB * 4, stream);

    // CSR build: counting sort, LDS atomics only (+50k block-level globals)
    binA_count<<<NBLK, 256, 0, stream>>>(row, bucket_count, bases, E, chunk, NB);
    bin_scan<<<1, 256, 0, stream>>>(bucket_count, bucket_start, NB);
    binA_scatter<<<NBLK, 256, 0, stream>>>(row, colv, ea, bucket_start, bases, bk, E, chunk, NB);
    binB<<<NB, 256, 0, stream>>>(bk, bucket_start, rowptr, edges, N);

    // soft -> bf16; w1, w2 -> packed bf16 fragments (x cvt fused into gemm128)
    const int ns2 = (N * 64) / 2;
    f32_to_bf16_kernel<<<(ns2 + 255) / 256, 256, 0, stream>>>(soft, softb, ns2);
    pack_w_kernel<128><<<8, 256, 0, stream>>>(w1, w1p);
    pack_w_kernel<64><<<4, 256, 0, stream>>>(w2, w2p);

    const int gGemm = (N + 63) / 64;
    const int gSp   = (N + 7) / 8;

    gemm_mfma_f32a<128><<<gGemm, 256, 0, stream>>>(x, w1p, xw1b, N);                  // xw1 (bf16)
    spmm128_relu<<<gSp, 256, 0, stream>>>(rowptr, edges, xw1b, b1, (unsigned*)hb, N); // h (bf16)
    gemm_mfma<64><<<gGemm, 256, 0, stream>>>(hb, w2p, logitsb, N);                    // logits
    spmm64_kernel<2, false><<<gSp, 256, 0, stream>>>(rowptr, edges, logitsb, b2, out0, N);

    spmm64_kernel<0, true ><<<gSp, 256, 0, stream>>>(rowptr, edges, softb, nullptr, labA, N);
    spmm64_kernel<0, true ><<<gSp, 256, 0, stream>>>(rowptr, edges, labA, nullptr, labB, N);
    spmm64_kernel<0, true ><<<gSp, 256, 0, stream>>>(rowptr, edges, labB, nullptr, labA, N);
    spmm64_kernel<0, true ><<<gSp, 256, 0, stream>>>(rowptr, edges, labA, nullptr, labB, N);
    spmm64_kernel<3, false><<<gSp, 256, 0, stream>>>(rowptr, edges, labB, nullptr, out1, N);
}

// Round 6
// 361.851 us; speedup vs baseline: 1.1566x; 1.1566x over previous
//
#include <hip/hip_runtime.h>
#include <cstdint>
#include <cstddef>

// ---------------------------------------------------------------------------
// GCN+LPA on MI355X.
// R6: R5's 2-row/wave MLP boost was neutral-to-negative -> gather path is
// saturated at the shared L2-miss/fabric random-request throughput, and the
// joint loop added drain overhead. Revert to 1-row/wave. Instead, cut gather
// PASSES by fusing independent spmms that share the SAME edge list (identical
// loop counts, zero divergence, metadata read once):
//   fused1: spmm128(xw1 -> h, bias+relu)  +  spmm64(soft -> lab1)
//   fused2: spmm64(logits -> out0, bias+sigmoid) + spmm64(lab1 -> lab2)
//   3 solo spmm64 for the dependent LPA tail.
// 7 gather passes -> 5. CSR build / MFMA gemms unchanged.
// NOTE: packing assumes N < 65536 (row/col fit 16 bits). N = 50000 here.
// ---------------------------------------------------------------------------

#define WS_ALIGN(x) (((x) + 255) & ~((size_t)255))

typedef __attribute__((ext_vector_type(8))) short short8;
typedef __attribute__((ext_vector_type(4))) float floatx4;

__device__ __forceinline__ unsigned short f2bf(float f) {
    unsigned u = __float_as_uint(f);
    u += 0x7fffu + ((u >> 16) & 1u);          // round-to-nearest-even
    return (unsigned short)(u >> 16);
}
__device__ __forceinline__ float bf2f(unsigned short h) {
    return __uint_as_float(((unsigned)h) << 16);
}
__device__ __forceinline__ float sigmoidf(float x) {
    return 1.f / (1.f + __expf(-x));
}

static const int NBLK = 256;   // blocks for binning passes
#define MAXNB 256              // max coarse buckets supported (N <= 65536)

// ---------------------------------------------------------------------------
// CSR build: 2-level counting sort, LDS atomics only.
// ---------------------------------------------------------------------------
__launch_bounds__(256)
__global__ void binA_count(const int* __restrict__ row, int* __restrict__ bucket_count,
                           int* __restrict__ bases, int E, int chunk, int NB)
{
    __shared__ int hist[MAXNB];
    const int t = threadIdx.x;
    const int blk = blockIdx.x;
    if (t < NB) hist[t] = 0;
    __syncthreads();
    const int s = blk * chunk;
    const int e = min(E, s + chunk);
    for (int i = s + t; i < e; i += 256)
        atomicAdd(&hist[row[i] >> 8], 1);
    __syncthreads();
    if (t < NB)
        bases[blk * NB + t] = atomicAdd(&bucket_count[t], hist[t]);
}

__launch_bounds__(256)
__global__ void bin_scan(const int* __restrict__ bucket_count, int* __restrict__ bucket_start,
                         int NB)
{
    __shared__ int s[256];
    const int t = threadIdx.x;
    int v = (t < NB) ? bucket_count[t] : 0;
    s[t] = v;
    __syncthreads();
    for (int off = 1; off < 256; off <<= 1) {
        int u = (t >= off) ? s[t - off] : 0;
        __syncthreads();
        s[t] += u;
        __syncthreads();
    }
    int excl = s[t] - v;
    if (t <= NB) bucket_start[t] = excl;   // t==NB: total == E
}

__launch_bounds__(256)
__global__ void binA_scatter(const int* __restrict__ row, const int* __restrict__ colv,
                             const float* __restrict__ ea,
                             const int* __restrict__ bucket_start, const int* __restrict__ bases,
                             int2* __restrict__ bk, int E, int chunk, int NB)
{
    __shared__ int cur[MAXNB];
    const int t = threadIdx.x;
    const int blk = blockIdx.x;
    if (t < NB) cur[t] = bucket_start[t] + bases[blk * NB + t];
    __syncthreads();
    const int s = blk * chunk;
    const int e = min(E, s + chunk);
    for (int i = s + t; i < e; i += 256) {
        int r = row[i];
        int bin = r >> 8;
        int pos = atomicAdd(&cur[bin], 1);
        bk[pos] = make_int2(((r & 255) << 16) | colv[i], __float_as_int(ea[i]));
    }
}

__launch_bounds__(256)
__global__ void binB(const int2* __restrict__ bk, const int* __restrict__ bucket_start,
                     int* __restrict__ rowptr, int2* __restrict__ edges, int N)
{
    __shared__ int cnt[256];
    __shared__ float deg[256];
    __shared__ float inv[256];
    __shared__ int excl_s[256];
    __shared__ int cur[256];
    __shared__ int scantmp[256];
    const int b = blockIdx.x;
    const int t = threadIdx.x;
    const int s = bucket_start[b];
    const int e = bucket_start[b + 1];
    cnt[t] = 0;
    deg[t] = 0.f;
    __syncthreads();
    for (int i = s + t; i < e; i += 256) {
        int2 v = bk[i];
        int rl = ((unsigned)v.x) >> 16;
        atomicAdd(&cnt[rl], 1);
        atomicAdd(&deg[rl], __int_as_float(v.y));
    }
    __syncthreads();
    const int myc = cnt[t];
    scantmp[t] = myc;
    __syncthreads();
    for (int off = 1; off < 256; off <<= 1) {
        int u = (t >= off) ? scantmp[t - off] : 0;
        __syncthreads();
        scantmp[t] += u;
        __syncthreads();
    }
    const int excl = scantmp[t] - myc;
    excl_s[t] = excl;
    float d = deg[t];
    inv[t] = (d > 0.f) ? 1.f / d : 0.f;
    cur[t] = 0;
    const int gr = b * 256 + t;
    if (gr <= N) rowptr[gr] = s + excl;
    __syncthreads();
    for (int i = s + t; i < e; i += 256) {
        int2 v = bk[i];
        int rl = ((unsigned)v.x) >> 16;
        int c = v.x & 0xffff;
        int p = s + excl_s[rl] + atomicAdd(&cur[rl], 1);
        edges[p] = make_int2(c, __float_as_int(__int_as_float(v.y) * inv[rl]));
    }
}

// ---------------------------------------------------------------------------
// Conversions / packing
// ---------------------------------------------------------------------------
__global__ void f32_to_bf16_kernel(const float* __restrict__ in, unsigned short* __restrict__ out,
                                   int n2)  // n2 = n/2 pairs
{
    int i = blockIdx.x * 256 + threadIdx.x;
    if (i < n2) {
        float2 v = ((const float2*)in)[i];
        unsigned p = (unsigned)f2bf(v.x) | ((unsigned)f2bf(v.y) << 16);
        ((unsigned*)out)[i] = p;
    }
}

// Pre-pack W[128,COLS] f32 -> bf16 in MFMA B-fragment order.
template<int COLS>
__global__ void pack_w_kernel(const float* __restrict__ W, unsigned short* __restrict__ Wp)
{
    const int total = (COLS / 16) * 4 * 64;
    int idx = blockIdx.x * 256 + threadIdx.x;
    if (idx >= total) return;
    const int l = idx & 63;
    const int t = (idx >> 6) & 3;
    const int ct = idx >> 8;
    const int kbase = t * 32 + (l >> 4) * 8;
    const int col = ct * 16 + (l & 15);
    unsigned short v[8];
#pragma unroll
    for (int j = 0; j < 8; ++j)
        v[j] = f2bf(W[(size_t)(kbase + j) * COLS + col]);
    uint4 o;
    o.x = (unsigned)v[0] | ((unsigned)v[1] << 16);
    o.y = (unsigned)v[2] | ((unsigned)v[3] << 16);
    o.z = (unsigned)v[4] | ((unsigned)v[5] << 16);
    o.w = (unsigned)v[6] | ((unsigned)v[7] << 16);
    *(uint4*)(Wp + (size_t)idx * 8) = o;
}

// ---------------------------------------------------------------------------
// MFMA GEMM (f32 A, fused cvt): C_bf16[M,COLS] = bf16(A_f32[M,128]) @ Wp.
// ---------------------------------------------------------------------------
template<int COLS>
__launch_bounds__(256)
__global__ void gemm_mfma_f32a(const float* __restrict__ A,
                               const unsigned short* __restrict__ Wp,
                               unsigned short* __restrict__ C, int M)
{
    const int wave = threadIdx.x >> 6;
    const int lane = threadIdx.x & 63;
    const int row0 = blockIdx.x * 64 + wave * 16;
    const int m = lane & 15;
    const int q = lane >> 4;

    const int arow = row0 + m;
    const bool avalid = arow < M;
    short8 a[4];
#pragma unroll
    for (int t = 0; t < 4; ++t) {
        if (avalid) {
            float4 f0 = *(const float4*)(A + (size_t)arow * 128 + t * 32 + q * 8);
            float4 f1 = *(const float4*)(A + (size_t)arow * 128 + t * 32 + q * 8 + 4);
            a[t][0] = (short)f2bf(f0.x); a[t][1] = (short)f2bf(f0.y);
            a[t][2] = (short)f2bf(f0.z); a[t][3] = (short)f2bf(f0.w);
            a[t][4] = (short)f2bf(f1.x); a[t][5] = (short)f2bf(f1.y);
            a[t][6] = (short)f2bf(f1.z); a[t][7] = (short)f2bf(f1.w);
        } else {
            a[t] = (short8)0;
        }
    }

#pragma unroll
    for (int ct = 0; ct < COLS / 16; ++ct) {
        floatx4 acc = {0.f, 0.f, 0.f, 0.f};
#pragma unroll
        for (int t = 0; t < 4; ++t) {
            short8 b = *(const short8*)(Wp + (size_t)((ct * 4 + t) * 64 + lane) * 8);
            acc = __builtin_amdgcn_mfma_f32_16x16x32_bf16(a[t], b, acc, 0, 0, 0);
        }
        const int col = ct * 16 + m;
#pragma unroll
        for (int r = 0; r < 4; ++r) {
            int orow = row0 + q * 4 + r;
            if (orow < M)
                C[(size_t)orow * COLS + col] = f2bf(acc[r]);
        }
    }
}

// MFMA GEMM (bf16 A): same structure, A already bf16.
template<int COLS>
__launch_bounds__(256)
__global__ void gemm_mfma(const unsigned short* __restrict__ A,
                          const unsigned short* __restrict__ Wp,
                          unsigned short* __restrict__ C, int M)
{
    const int wave = threadIdx.x >> 6;
    const int lane = threadIdx.x & 63;
    const int row0 = blockIdx.x * 64 + wave * 16;
    const int m = lane & 15;
    const int q = lane >> 4;

    const int arow = row0 + m;
    const bool avalid = arow < M;
    short8 a[4];
#pragma unroll
    for (int t = 0; t < 4; ++t) {
        if (avalid)
            a[t] = *(const short8*)(A + (size_t)arow * 128 + t * 32 + q * 8);
        else
            a[t] = (short8)0;
    }

#pragma unroll
    for (int ct = 0; ct < COLS / 16; ++ct) {
        floatx4 acc = {0.f, 0.f, 0.f, 0.f};
#pragma unroll
        for (int t = 0; t < 4; ++t) {
            short8 b = *(const short8*)(Wp + (size_t)((ct * 4 + t) * 64 + lane) * 8);
            acc = __builtin_amdgcn_mfma_f32_16x16x32_bf16(a[t], b, acc, 0, 0, 0);
        }
        const int col = ct * 16 + m;
#pragma unroll
        for (int r = 0; r < 4; ++r) {
            int orow = row0 + q * 4 + r;
            if (orow < M)
                C[(size_t)orow * COLS + col] = f2bf(acc[r]);
        }
    }
}

// ---------------------------------------------------------------------------
// FUSED 1: F=128 stream (xw1 -> h, bias+relu, packed bf16x2 out)
//        + F=64 stream (soft -> lab1, bf16 out). Same edge list -> no diverge.
// One wave per row, 8-edge bursts, 3 gathers/edge in flight.
// ---------------------------------------------------------------------------
__launch_bounds__(256)
__global__ void spmm_f128_f64(const int* __restrict__ rowptr, const int2* __restrict__ edges,
                              const unsigned* __restrict__ srcA,        // xw1 packed bf16x2
                              const unsigned short* __restrict__ srcB,  // softb
                              const float* __restrict__ bias,
                              unsigned* __restrict__ outA,              // h packed bf16x2
                              unsigned short* __restrict__ outB,        // lab1 bf16
                              int n)
{
    const int row = blockIdx.x * 4 + (threadIdx.x >> 6);
    const int lane = threadIdx.x & 63;
    if (row >= n) return;
    const int s = rowptr[row];
    const int e = rowptr[row + 1];

    float ax[8], ay[8], ab[8];
#pragma unroll
    for (int j = 0; j < 8; ++j) { ax[j] = 0.f; ay[j] = 0.f; ab[j] = 0.f; }
    int i = s;
    for (; i + 8 <= e; i += 8) {
        int2 ed[8];
        unsigned ua[8];
        unsigned short ub[8];
#pragma unroll
        for (int j = 0; j < 8; ++j) ed[j] = edges[i + j];
#pragma unroll
        for (int j = 0; j < 8; ++j) ua[j] = srcA[(size_t)ed[j].x * 64 + lane];
#pragma unroll
        for (int j = 0; j < 8; ++j) ub[j] = srcB[(size_t)ed[j].x * 64 + lane];
#pragma unroll
        for (int j = 0; j < 8; ++j) {
            float w = __int_as_float(ed[j].y);
            ax[j] = fmaf(w, __uint_as_float(ua[j] << 16), ax[j]);
            ay[j] = fmaf(w, __uint_as_float(ua[j] & 0xffff0000u), ay[j]);
            ab[j] = fmaf(w, bf2f(ub[j]), ab[j]);
        }
    }
    for (; i < e; ++i) {
        int2 e0 = edges[i];
        unsigned ua = srcA[(size_t)e0.x * 64 + lane];
        unsigned short ub = srcB[(size_t)e0.x * 64 + lane];
        float w = __int_as_float(e0.y);
        ax[0] = fmaf(w, __uint_as_float(ua << 16), ax[0]);
        ay[0] = fmaf(w, __uint_as_float(ua & 0xffff0000u), ay[0]);
        ab[0] = fmaf(w, bf2f(ub), ab[0]);
    }
    float vx = ((ax[0] + ax[1]) + (ax[2] + ax[3])) + ((ax[4] + ax[5]) + (ax[6] + ax[7]));
    float vy = ((ay[0] + ay[1]) + (ay[2] + ay[3])) + ((ay[4] + ay[5]) + (ay[6] + ay[7]));
    float vb = ((ab[0] + ab[1]) + (ab[2] + ab[3])) + ((ab[4] + ab[5]) + (ab[6] + ab[7]));
    float2 b = *(const float2*)(bias + lane * 2);
    vx = fmaxf(vx + b.x, 0.f);
    vy = fmaxf(vy + b.y, 0.f);
    outA[(size_t)row * 64 + lane] = (unsigned)f2bf(vx) | ((unsigned)f2bf(vy) << 16);
    outB[(size_t)row * 64 + lane] = f2bf(vb);
}

// ---------------------------------------------------------------------------
// FUSED 2: two F=64 streams. A: logits -> out0 (bias+sigmoid, f32 out).
//          B: lab1 -> lab2 (no act, bf16 out).
// ---------------------------------------------------------------------------
__launch_bounds__(256)
__global__ void spmm_f64_f64(const int* __restrict__ rowptr, const int2* __restrict__ edges,
                             const unsigned short* __restrict__ srcA,   // logitsb
                             const unsigned short* __restrict__ srcB,   // lab1
                             const float* __restrict__ bias,
                             float* __restrict__ outA,                  // out0 f32
                             unsigned short* __restrict__ outB,         // lab2 bf16
                             int n)
{
    const int row = blockIdx.x * 4 + (threadIdx.x >> 6);
    const int lane = threadIdx.x & 63;
    if (row >= n) return;
    const int s = rowptr[row];
    const int e = rowptr[row + 1];

    float aa[8], ab[8];
#pragma unroll
    for (int j = 0; j < 8; ++j) { aa[j] = 0.f; ab[j] = 0.f; }
    int i = s;
    for (; i + 8 <= e; i += 8) {
        int2 ed[8];
        unsigned short ua[8], ub[8];
#pragma unroll
        for (int j = 0; j < 8; ++j) ed[j] = edges[i + j];
#pragma unroll
        for (int j = 0; j < 8; ++j) ua[j] = srcA[(size_t)ed[j].x * 64 + lane];
#pragma unroll
        for (int j = 0; j < 8; ++j) ub[j] = srcB[(size_t)ed[j].x * 64 + lane];
#pragma unroll
        for (int j = 0; j < 8; ++j) {
            float w = __int_as_float(ed[j].y);
            aa[j] = fmaf(w, bf2f(ua[j]), aa[j]);
            ab[j] = fmaf(w, bf2f(ub[j]), ab[j]);
        }
    }
    for (; i < e; ++i) {
        int2 e0 = edges[i];
        float w = __int_as_float(e0.y);
        aa[0] = fmaf(w, bf2f(srcA[(size_t)e0.x * 64 + lane]), aa[0]);
        ab[0] = fmaf(w, bf2f(srcB[(size_t)e0.x * 64 + lane]), ab[0]);
    }
    float va = ((aa[0] + aa[1]) + (aa[2] + aa[3])) + ((aa[4] + aa[5]) + (aa[6] + aa[7]));
    float vb = ((ab[0] + ab[1]) + (ab[2] + ab[3])) + ((ab[4] + ab[5]) + (ab[6] + ab[7]));
    outA[(size_t)row * 64 + lane] = sigmoidf(va + bias[lane]);
    outB[(size_t)row * 64 + lane] = f2bf(vb);
}

// ---------------------------------------------------------------------------
// Solo SpMM F=64, bf16 src. ACT: 0 none, 3 sigmoid. OUT_BF16: bf16 else f32.
// R4 structure (1 row/wave, 8-deep bursts).
// ---------------------------------------------------------------------------
template<int ACT, bool OUT_BF16>
__launch_bounds__(256)
__global__ void spmm64_kernel(const int* __restrict__ rowptr, const int2* __restrict__ edges,
                              const unsigned short* __restrict__ src,
                              void* __restrict__ out, int n)
{
    const int row = blockIdx.x * 4 + (threadIdx.x >> 6);
    const int lane = threadIdx.x & 63;
    if (row >= n) return;
    const int s = rowptr[row];
    const int e = rowptr[row + 1];

    float a[8];
#pragma unroll
    for (int j = 0; j < 8; ++j) a[j] = 0.f;
    int i = s;
    for (; i + 8 <= e; i += 8) {
        int2 ed[8];
        float sv[8];
#pragma unroll
        for (int j = 0; j < 8; ++j) ed[j] = edges[i + j];
#pragma unroll
        for (int j = 0; j < 8; ++j) sv[j] = bf2f(src[(size_t)ed[j].x * 64 + lane]);
#pragma unroll
        for (int j = 0; j < 8; ++j) a[j] = fmaf(__int_as_float(ed[j].y), sv[j], a[j]);
    }
    for (; i < e; ++i) {
        int2 e0 = edges[i];
        a[0] = fmaf(__int_as_float(e0.y), bf2f(src[(size_t)e0.x * 64 + lane]), a[0]);
    }
    float v = ((a[0] + a[1]) + (a[2] + a[3])) + ((a[4] + a[5]) + (a[6] + a[7]));
    if (ACT == 3) v = sigmoidf(v);
    if (OUT_BF16)
        ((unsigned short*)out)[(size_t)row * 64 + lane] = f2bf(v);
    else
        ((float*)out)[(size_t)row * 64 + lane] = v;
}

// ---------------------------------------------------------------------------
extern "C" void kernel_launch(void* const* d_in, const int* in_sizes, int n_in,
                              void* d_out, int out_size, void* d_ws, size_t ws_size,
                              hipStream_t stream)
{
    const float* x    = (const float*)d_in[0];
    const float* soft = (const float*)d_in[1];
    const float* ea   = (const float*)d_in[2];
    const float* w1   = (const float*)d_in[3];
    const float* b1   = (const float*)d_in[4];
    const float* w2   = (const float*)d_in[5];
    const float* b2   = (const float*)d_in[6];
    const int*   eidx = (const int*)d_in[7];

    const int N = in_sizes[0] / 128;
    const int E = in_sizes[2];
    const int* row  = eidx;
    const int* colv = eidx + E;
    const int NB = (N + 255) / 256;            // coarse buckets (<= 256)
    const int chunk = (E + NBLK - 1) / NBLK;

    uint8_t* ws = (uint8_t*)d_ws;
    size_t off = 0;
    auto alloc = [&](size_t bytes) -> void* {
        void* p = ws + off;
        off += WS_ALIGN(bytes);
        return p;
    };
    int*  bucket_count = (int*) alloc((size_t)NB * 4);
    int*  bucket_start = (int*) alloc(((size_t)NB + 1) * 4);
    int*  bases        = (int*) alloc((size_t)NBLK * NB * 4);
    int*  rowptr       = (int*) alloc(((size_t)N + 1) * 4);
    int2* bk           = (int2*)alloc((size_t)E * 8);
    int2* edges        = (int2*)alloc((size_t)E * 8);
    unsigned short* w1p     = (unsigned short*)alloc((size_t)128 * 128 * 2);
    unsigned short* w2p     = (unsigned short*)alloc((size_t)128 * 64 * 2);
    unsigned short* xw1b    = (unsigned short*)alloc((size_t)N * 128 * 2);
    unsigned short* hb      = (unsigned short*)alloc((size_t)N * 128 * 2);
    unsigned short* logitsb = (unsigned short*)alloc((size_t)N * 64 * 2);
    unsigned short* softb   = (unsigned short*)alloc((size_t)N * 64 * 2);
    unsigned short* labA    = (unsigned short*)alloc((size_t)N * 64 * 2);
    unsigned short* labB    = (unsigned short*)alloc((size_t)N * 64 * 2);

    float* out0 = (float*)d_out;             // x_out [N,64]
    float* out1 = out0 + (size_t)N * 64;     // labels [N,64]

    hipMemsetAsync(bucket_count, 0, (size_t)NB * 4, stream);

    // CSR build: counting sort, LDS atomics only (+50k block-level globals)
    binA_count<<<NBLK, 256, 0, stream>>>(row, bucket_count, bases, E, chunk, NB);
    bin_scan<<<1, 256, 0, stream>>>(bucket_count, bucket_start, NB);
    binA_scatter<<<NBLK, 256, 0, stream>>>(row, colv, ea, bucket_start, bases, bk, E, chunk, NB);
    binB<<<NB, 256, 0, stream>>>(bk, bucket_start, rowptr, edges, N);

    // soft -> bf16; w1, w2 -> packed bf16 fragments (x cvt fused into gemm128)
    const int ns2 = (N * 64) / 2;
    f32_to_bf16_kernel<<<(ns2 + 255) / 256, 256, 0, stream>>>(soft, softb, ns2);
    pack_w_kernel<128><<<8, 256, 0, stream>>>(w1, w1p);
    pack_w_kernel<64><<<4, 256, 0, stream>>>(w2, w2p);

    const int gGemm = (N + 63) / 64;
    const int gSp   = (N + 3) / 4;

    gemm_mfma_f32a<128><<<gGemm, 256, 0, stream>>>(x, w1p, xw1b, N);     // xw1 (bf16)

    // fused pass 1: h = relu(spmm(xw1)+b1), lab1 = spmm(soft)
    spmm_f128_f64<<<gSp, 256, 0, stream>>>(rowptr, edges, (const unsigned*)xw1b, softb,
                                           b1, (unsigned*)hb, labA, N);

    gemm_mfma<64><<<gGemm, 256, 0, stream>>>(hb, w2p, logitsb, N);       // logits (bf16)

    // fused pass 2: out0 = sigmoid(spmm(logits)+b2), lab2 = spmm(lab1)
    spmm_f64_f64<<<gSp, 256, 0, stream>>>(rowptr, edges, logitsb, labA, b2, out0, labB, N);

    // LPA tail (dependent): lab3, lab4, out1
    spmm64_kernel<0, true ><<<gSp, 256, 0, stream>>>(rowptr, edges, labB, labA, N);
    spmm64_kernel<0, true ><<<gSp, 256, 0, stream>>>(rowptr, edges, labA, labB, N);
    spmm64_kernel<3, false><<<gSp, 256, 0, stream>>>(rowptr, edges, labB, out1, N);
}